// Round 10
// baseline (347.359 us; speedup 1.0000x reference)
//
#include <hip/hip_runtime.h>
#include <stdint.h>

typedef unsigned int u32;
typedef unsigned long long u64;
typedef unsigned short u16;
typedef unsigned short ushort_t;
typedef short bf16x8 __attribute__((ext_vector_type(8)));
typedef float f32x4  __attribute__((ext_vector_type(4)));

// Problem constants
#define NQ    8192
#define DIMK  256
#define NE    16384
#define CSTR  1024
#define BSTR  262144

#define SLOTS 128
#define CMARG 2.5e-4f   // np tie window (~9e-5) + 2x worst-case bf16 rnd error

// ws layout (bytes): total 10,649,856 <= 10,682,624 proven in round 4
#define WS_EE    256        // float ee[16384]
#define WS_ZZ    65792      // float zz[8192]
#define WS_GMIN  98560      // u32 gmin[8192]
#define WS_CNT   131328     // u32 cnt[8192]
#define WS_CAND  164096     // u16 cand[8192*128] = 2 MB
#define WS_EP    2261248    // ushort Ep[16384*256] = 8 MB (permuted bf16 E)

__device__ __forceinline__ u32 fmap(float f) {
    union { float f; u32 u; } x; x.f = f;
    return (x.u & 0x80000000u) ? ~x.u : (x.u | 0x80000000u);
}
__device__ __forceinline__ float funmap(u32 u) {
    union { float f; u32 u; } x;
    x.u = (u & 0x80000000u) ? (u ^ 0x80000000u) : ~u;
    return x.f;
}
// pack two fp32 -> two bf16 (round-half-up; error budget covered by CMARG, proven R4-R9)
__device__ __forceinline__ u32 pkbf(float lo, float hi) {
    u32 a = __float_as_uint(lo) + 0x8000u;
    u32 b = __float_as_uint(hi) + 0x8000u;
    return __builtin_amdgcn_perm(b, a, 0x07060302u);
}

// ---- numpy einsum dot replica: SSE baseline (W=4, no FMA) — validated R3-R9 ----
__device__ __forceinline__ float np_einsum_dot(const float* __restrict__ zr, int zstride,
                                               const float* __restrict__ er) {
    float a0 = 0.0f, a1 = 0.0f, a2 = 0.0f, a3 = 0.0f;
    for (int s = 0; s < 64; ++s) {
        const int k = s * 4;
        a0 = __fadd_rn(a0, __fmul_rn(zr[(size_t)(k + 0) * zstride], er[k + 0]));
        a1 = __fadd_rn(a1, __fmul_rn(zr[(size_t)(k + 1) * zstride], er[k + 1]));
        a2 = __fadd_rn(a2, __fmul_rn(zr[(size_t)(k + 2) * zstride], er[k + 2]));
        a3 = __fadd_rn(a3, __fmul_rn(zr[(size_t)(k + 3) * zstride], er[k + 3]));
    }
    return __fadd_rn(__fadd_rn(a0, a1), __fadd_rn(a2, a3));
}

// blocks 0..1023: E rows (ee + Ep permuted-bf16 conversion); 1024..1535: z rows (zz + init)
__global__ __launch_bounds__(256)
void k_prep(const float* __restrict__ z, const float* __restrict__ E,
            float* __restrict__ ee, float* __restrict__ zz,
            u32* __restrict__ gmin, u32* __restrict__ cnt, float* __restrict__ acc,
            ushort_t* __restrict__ Ep) {
    const int t = threadIdx.x;
    const int bid = blockIdx.x;
    if (bid == 0 && t == 0) *acc = 0.0f;
    const int g = t >> 4, s = t & 15;
    const int row = bid * 16 + g;
    const float* p;
    int stride;
    if (row < NE) { p = E + (size_t)row * DIMK; stride = 1; }
    else {
        const int q = row - NE;
        const int b = q >> 10, hw = q & 1023;
        p = z + (size_t)b * BSTR + hw; stride = CSTR;
        if (s == 0) { gmin[q] = 0xFFFFFFFFu; cnt[q] = 0u; }
    }
    // np pairwise sum of squares, 16 lanes/row (bitwise np order via fadd commutativity)
    const int h = s >> 3, j = s & 7;
    const float* pp = p + (size_t)(h * 128 + j) * stride;
    float v = pp[0];
    float r = __fmul_rn(v, v);
    for (int i = 1; i < 16; ++i) {
        v = pp[(size_t)(i * 8) * stride];
        r = __fadd_rn(r, __fmul_rn(v, v));
    }
    r = __fadd_rn(r, __shfl_xor(r, 1, 16));
    r = __fadd_rn(r, __shfl_xor(r, 2, 16));
    r = __fadd_rn(r, __shfl_xor(r, 4, 16));
    r = __fadd_rn(r, __shfl_xor(r, 8, 16));
    if (s == 0) {
        if (row < NE) ee[row] = r;
        else          zz[row - NE] = r;
    }
    if (bid < 1024) {
        // Ep: chunk c = kc*64 + quad*16 + l15 holds bf16 E[bid*16+l15][kc*32+quad*8 .. +7]
#pragma unroll
        for (int i = 0; i < 2; ++i) {
            const int c    = t + i * 256;
            const int kc   = c >> 6;
            const int lane = c & 63;
            const int quad = lane >> 4, l15 = lane & 15;
            const float* src = E + (size_t)(bid * 16 + l15) * DIMK + kc * 32 + quad * 8;
            float4 f0 = *(const float4*)(src);
            float4 f1 = *(const float4*)(src + 4);
            uint4 pk;
            pk.x = pkbf(f0.x, f0.y); pk.y = pkbf(f0.z, f0.w);
            pk.z = pkbf(f1.x, f1.y); pk.w = pkbf(f1.z, f1.w);
            *(uint4*)((char*)Ep + (size_t)bid * 8192 + (size_t)c * 16) = pk;
        }
    }
}

// ---- shared GEMM skeleton pieces for the two filter passes ----
// stage A (z 128x256 -> bf16 LDS swizzled) then A fragments into registers.
#define FILTER_PROLOGUE                                                               \
    __shared__ ushort_t Az[32768];                                                    \
    char* lds = (char*)Az;                                                            \
    const int t     = threadIdx.x;                                                    \
    const int bid   = blockIdx.x;                                                     \
    const int chunk = bid & 7;                                                        \
    const int rb    = bid >> 3;                                                       \
    const int n0    = rb * 128;                                                       \
    const int j0c   = chunk * 2048;                                                   \
    const int b     = n0 >> 10, hw0 = n0 & 1023;                                      \
    const int w     = t >> 6, lane = t & 63, quad = lane >> 4, l15 = lane & 15;       \
    const int wr    = (w >> 1) * 64, wc = (w & 1) * 64;                               \
    {                                                                                 \
        const int rbase = (t & 31) * 4;                                               \
        const int ksub  = (t >> 5) * 2;                                               \
        for (int p = 0; p < 16; ++p) {                                                \
            const int k0 = p * 16 + ksub;                                             \
            float4 f0 = *(const float4*)(z + (size_t)b * BSTR + (size_t)k0 * CSTR + hw0 + rbase); \
            float4 f1 = *(const float4*)(z + (size_t)b * BSTR + (size_t)(k0 + 1) * CSTR + hw0 + rbase); \
            const float a0[4] = {f0.x, f0.y, f0.z, f0.w};                             \
            const float a1[4] = {f1.x, f1.y, f1.z, f1.w};                             \
            _Pragma("unroll")                                                         \
            for (int i = 0; i < 4; ++i) {                                             \
                const int row = rbase + i;                                            \
                *(u32*)(lds + row * 512 + ((k0 * 2) ^ ((row & 7) << 4))) = pkbf(a0[i], a1[i]); \
            }                                                                         \
        }                                                                             \
    }                                                                                 \
    __syncthreads();                                                                  \
    bf16x8 af[4][8];                                                                  \
    _Pragma("unroll")                                                                 \
    for (int fi = 0; fi < 4; ++fi) {                                                  \
        const int row = wr + fi * 16 + l15;                                           \
        _Pragma("unroll")                                                             \
        for (int kc = 0; kc < 8; ++kc)                                                \
            af[fi][kc] = *(const bf16x8*)(lds + row * 512 + ((kc * 64 + quad * 16) ^ ((row & 7) << 4))); \
    }                                                                                 \
    const int cbase = (j0c + wc) >> 4;                                                \
    const size_t lofs = (size_t)lane * 8;                                             \
    bf16x8 bufA[4], bufB[4];

#define LOADB(dst, ct, kc)                                                        \
    {                                                                             \
        const int bg = cbase + (ct) * 8;                                          \
        const size_t ko = (size_t)((kc) * 64) * 8 + lofs;                         \
        _Pragma("unroll")                                                         \
        for (int fj = 0; fj < 4; ++fj)                                            \
            dst[fj] = *(const bf16x8*)(Ep + (size_t)(bg + fj) * 4096 + ko);       \
    }

#define GEMM_TILE(it)                                                             \
    f32x4 acc[4][4];                                                              \
    _Pragma("unroll")                                                             \
    for (int fi = 0; fi < 4; ++fi)                                                \
        _Pragma("unroll")                                                         \
        for (int fj = 0; fj < 4; ++fj)                                            \
            _Pragma("unroll")                                                     \
            for (int r = 0; r < 4; ++r) acc[fi][fj][r] = 0.0f;                    \
    _Pragma("unroll")                                                             \
    for (int kc = 0; kc < 8; ++kc) {                                              \
        int nit = (it), nkc = kc + 1;                                             \
        if (nkc == 8) { nkc = 0; nit = (it) + 1; }                                \
        const int nct = (nit >= 16) ? 0 : nit;                                    \
        if (kc & 1) {                                                             \
            LOADB(bufA, nct, nkc);                                                \
            _Pragma("unroll")                                                     \
            for (int fi = 0; fi < 4; ++fi)                                        \
                _Pragma("unroll")                                                 \
                for (int fj = 0; fj < 4; ++fj)                                    \
                    acc[fi][fj] = __builtin_amdgcn_mfma_f32_16x16x32_bf16(        \
                        af[fi][kc], bufB[fj], acc[fi][fj], 0, 0, 0);              \
        } else {                                                                  \
            LOADB(bufB, nct, nkc);                                                \
            _Pragma("unroll")                                                     \
            for (int fi = 0; fi < 4; ++fi)                                        \
                _Pragma("unroll")                                                 \
                for (int fj = 0; fj < 4; ++fj)                                    \
                    acc[fi][fj] = __builtin_amdgcn_mfma_f32_16x16x32_bf16(        \
                        af[fi][kc], bufA[fj], acc[fi][fj], 0, 0, 0);              \
        }                                                                         \
    }

// PASS 1: pure GEMM + per-lane running min (NO LDS/atomics/ballots in loop),
// one cross-lane reduce + global atomicMin per row at the end.
__global__ __launch_bounds__(256, 2)
void k_fmin(const float* __restrict__ z, const ushort_t* __restrict__ Ep,
            const float* __restrict__ ee, u32* __restrict__ gmin) {
    FILTER_PROLOGUE
    float mins[16];
#pragma unroll
    for (int i = 0; i < 16; ++i) mins[i] = 3.402823e38f;

    LOADB(bufA, 0, 0);
    for (int it = 0; it < 16; ++it) {
        const int j0 = j0c + it * 128;
        float eev[4];
#pragma unroll
        for (int fj = 0; fj < 4; ++fj) eev[fj] = ee[j0 + wc + fj * 16 + l15];
        GEMM_TILE(it)
#pragma unroll
        for (int fi = 0; fi < 4; ++fi)
#pragma unroll
            for (int r = 0; r < 4; ++r) {
                float m = fminf(fminf(fmaf(-2.0f, acc[fi][0][r], eev[0]),
                                      fmaf(-2.0f, acc[fi][1][r], eev[1])),
                                fminf(fmaf(-2.0f, acc[fi][2][r], eev[2]),
                                      fmaf(-2.0f, acc[fi][3][r], eev[3])));
                mins[fi * 4 + r] = fminf(mins[fi * 4 + r], m);
            }
    }
    // cross-lane (l15) reduce, then one device atomicMin per row
#pragma unroll
    for (int fi = 0; fi < 4; ++fi)
#pragma unroll
        for (int r = 0; r < 4; ++r) {
            float m = mins[fi * 4 + r];
            m = fminf(m, __shfl_xor(m, 1, 16));
            m = fminf(m, __shfl_xor(m, 2, 16));
            m = fminf(m, __shfl_xor(m, 4, 16));
            m = fminf(m, __shfl_xor(m, 8, 16));
            if (l15 == 0) atomicMin(&gmin[n0 + wr + fi * 16 + quad * 4 + r], fmap(m));
        }
}

// PASS 2: same GEMM; fixed per-row thresholds (exact min + CMARG) loaded once;
// rare ballot-gated collect. Completeness: v(np-winner) <= vmin + CMARG (proven).
__global__ __launch_bounds__(256, 2)
void k_fcollect(const float* __restrict__ z, const ushort_t* __restrict__ Ep,
                const float* __restrict__ ee, const u32* __restrict__ gmin,
                u32* __restrict__ cnt, u16* __restrict__ cand) {
    FILTER_PROLOGUE
    float thrv[16];
#pragma unroll
    for (int fi = 0; fi < 4; ++fi)
#pragma unroll
        for (int r = 0; r < 4; ++r)
            thrv[fi * 4 + r] = funmap(gmin[n0 + wr + fi * 16 + quad * 4 + r]) + CMARG;

    LOADB(bufA, 0, 0);
    for (int it = 0; it < 16; ++it) {
        const int j0 = j0c + it * 128;
        float eev[4];
#pragma unroll
        for (int fj = 0; fj < 4; ++fj) eev[fj] = ee[j0 + wc + fj * 16 + l15];
        GEMM_TILE(it)
#pragma unroll
        for (int fi = 0; fi < 4; ++fi)
#pragma unroll
            for (int r = 0; r < 4; ++r) {
                float vv[4];
#pragma unroll
                for (int fj = 0; fj < 4; ++fj) vv[fj] = fmaf(-2.0f, acc[fi][fj][r], eev[fj]);
                const float thr = thrv[fi * 4 + r];
                const float lmin = fminf(fminf(vv[0], vv[1]), fminf(vv[2], vv[3]));
                if (__any(lmin <= thr)) {   // rare (~3 collects/row over all tiles)
                    const int rg = n0 + wr + fi * 16 + quad * 4 + r;
#pragma unroll
                    for (int fj = 0; fj < 4; ++fj) {
                        if (vv[fj] <= thr) {
                            u32 p = atomicAdd(&cnt[rg], 1u);
                            if (p < SLOTS)
                                cand[(size_t)rg * SLOTS + p] = (u16)(j0 + wc + fj * 16 + l15);
                        }
                    }
                }
            }
    }
}

// numpy-bitwise rescore of ALL collected candidates (winner provably in set)
__global__ __launch_bounds__(64)
void k_rescore(const float* __restrict__ z, const float* __restrict__ E,
               const float* __restrict__ zz, const float* __restrict__ ee,
               const u32* __restrict__ cnt, const u16* __restrict__ cand,
               float* __restrict__ out_idx) {
    const int q = blockIdx.x;
    const int t = threadIdx.x;
    const int b = q >> 10, hw = q & 1023;
    const u32 n = min(cnt[q], (u32)SLOTS);

    u64 best = 0xFFFFFFFFFFFFFFFFULL;
#pragma unroll
    for (int s = 0; s < 2; ++s) {
        const u32 slot = (u32)t + s * 64;
        if (slot < n) {
            const int j = (int)cand[(size_t)q * SLOTS + slot] & (NE - 1);   // OOB-proof
            const float ze = np_einsum_dot(z + (size_t)b * BSTR + hw, CSTR, E + (size_t)j * DIMK);
            const float t1 = __fadd_rn(zz[q], ee[j]);
            const float d  = __fsub_rn(t1, __fmul_rn(2.0f, ze));
            u64 key = ((u64)fmap(d) << 32) | (u32)j;   // ties -> lowest j
            if (key < best) best = key;
        }
    }
#pragma unroll
    for (int off = 1; off < 64; off <<= 1) {
        u64 o = __shfl_xor(best, off, 64);
        if (o < best) best = o;
    }
    if (t == 0) out_idx[q] = (float)((int)(best & 0xFFFFFFFFULL) & (NE - 1));
}

// gather + transpose + loss; 256 blocks (32 q-groups x 8 c-groups)
__global__ __launch_bounds__(256)
void k_finalize(const float* __restrict__ z, const float* __restrict__ E,
                const float* __restrict__ out_idx,
                float* __restrict__ out0, float* __restrict__ acc) {
    __shared__ float T[256 * 33];
    __shared__ float red[256];
    const int t  = threadIdx.x;
    const int qg = blockIdx.x >> 3;
    const int ch = blockIdx.x & 7;
    const int q0 = qg * 256;
    const int c0 = ch * 32;
    const int b  = q0 >> 10, hw0 = q0 & 1023;
    const int idx = ((int)out_idx[q0 + t]) & (NE - 1);
    const float* er = E + (size_t)idx * DIMK + c0;
#pragma unroll
    for (int i = 0; i < 8; ++i) {
        float4 f = *(const float4*)(er + i * 4);
        T[t * 33 + i * 4 + 0] = f.x;
        T[t * 33 + i * 4 + 1] = f.y;
        T[t * 33 + i * 4 + 2] = f.z;
        T[t * 33 + i * 4 + 3] = f.w;
    }
    __syncthreads();
    float ls = 0.0f;
#pragma unroll 4
    for (int cc = 0; cc < 32; ++cc) {
        const float ev = T[t * 33 + cc];
        const size_t o = (size_t)b * BSTR + (size_t)(c0 + cc) * CSTR + hw0 + t;
        const float d = ev - z[o];
        ls = fmaf(d, d, ls);
        out0[o] = ev;
    }
    red[t] = ls;
    __syncthreads();
    for (int s = 128; s > 0; s >>= 1) {
        if (t < s) red[t] += red[t + s];
        __syncthreads();
    }
    if (t == 0) atomicAdd(acc, red[0]);
}

__global__ void k_loss(const float* __restrict__ acc, float* __restrict__ out_loss) {
    *out_loss = 1.25f * (*acc) * (1.0f / 2097152.0f);
}

extern "C" void kernel_launch(void* const* d_in, const int* in_sizes, int n_in,
                              void* d_out, int out_size, void* d_ws, size_t ws_size,
                              hipStream_t stream) {
    const float* z = (const float*)d_in[0];   // [8,256,32,32] fp32
    const float* E = (const float*)d_in[1];   // [16384,256] fp32

    float* out0     = (float*)d_out;
    float* out_loss = (float*)d_out + 2097152;
    float* out_idx  = (float*)d_out + 2097153;

    float*    acc  = (float*)d_ws;
    float*    ee   = (float*)((char*)d_ws + WS_EE);
    float*    zz   = (float*)((char*)d_ws + WS_ZZ);
    u32*      gmin = (u32*)  ((char*)d_ws + WS_GMIN);
    u32*      cnt  = (u32*)  ((char*)d_ws + WS_CNT);
    u16*      cand = (u16*)  ((char*)d_ws + WS_CAND);
    ushort_t* Ep   = (ushort_t*)((char*)d_ws + WS_EP);

    k_prep<<<1536, 256, 0, stream>>>(z, E, ee, zz, gmin, cnt, acc, Ep);
    k_fmin<<<512, 256, 0, stream>>>(z, Ep, ee, gmin);
    k_fcollect<<<512, 256, 0, stream>>>(z, Ep, ee, gmin, cnt, cand);
    k_rescore<<<NQ, 64, 0, stream>>>(z, E, zz, ee, cnt, cand, out_idx);
    k_finalize<<<256, 256, 0, stream>>>(z, E, out_idx, out0, acc);
    k_loss<<<1, 1, 0, stream>>>(acc, out_loss);
}